// Round 5
// baseline (260.926 us; speedup 1.0000x reference)
//
#include <hip/hip_runtime.h>
#include <math.h>

#define NH 49152
#define KI 1024
#define DD 32
#define HF 256

// float-index layout in ws  (~9.3 MB total)
#define WS_PART  0                    // [0]=vrep [1]=vatt [2]=noise_sum [3]=n_noise(u32) [4]=sum(1-beta_a)
#define WS_SEG64 8                    // KI u64 packed (q_bits<<32 | NH-1-h)
#define WS_A12   (WS_SEG64 + 2*KI)    // KI*12: d0..7, ca, qa, pad2
#define WS_H12   (WS_A12 + 12*KI)     // NH*12: d0..7, ch, q, bc, pad
#define WS_XA    (WS_H12 + 12*NH)     // KI*DD full alpha coords
#define WS_OX    (WS_XA + KI*DD)      // NH*DD (atomic-accumulated)
#define WS_ZB    (WS_OX + NH*DD)      // NH beta-logit partial sums

// zero OX (393216 float4), ZB, seg64, parts
__global__ __launch_bounds__(256) void k_init(float* __restrict__ ws) {
    const int i = blockIdx.x * 256 + threadIdx.x;
    const float4 z4 = {0.0f, 0.0f, 0.0f, 0.0f};
    *(float4*)(ws + WS_OX + (size_t)i * 4) = z4;
    if (i < 12288) *(float4*)(ws + WS_ZB + (size_t)i * 4) = z4;
    if (i < 512)   *(float4*)(ws + WS_SEG64 + (size_t)i * 4) = z4;
    if (i == 0) { *(float4*)(ws + WS_PART) = z4; *(float4*)(ws + WS_PART + 4) = z4; }
}

// GEMM, K-split x2: block = (tile of 128 hits) x (128 k-rows).
// grid 768 -> 3 blocks/CU, 12 waves/CU. W-half = 16.4 KB -> fits scalar L1;
// W read via wave-uniform pointers (s_load). x staged transposed in LDS.
__global__ __launch_bounds__(256, 3) void k_gemm(
        const float* __restrict__ x, const float* __restrict__ Wb,
        const float* __restrict__ bb, const float* __restrict__ Wc,
        const float* __restrict__ bcrd, float* __restrict__ ws) {
    __shared__ float xsT[32][132];    // [k-in-chunk][hit], even pad -> aligned b64
    const int t  = threadIdx.x;
    const int l  = t & 63;
    const int g  = __builtin_amdgcn_readfirstlane(t >> 6);
    const int h0 = (blockIdx.x >> 1) * 128;
    const int kh = blockIdx.x & 1;
    const int K0 = kh * 128;

    const int srow = t >> 3;          // hit base 0..31
    const int scol = (t & 7) * 4;     // k offset 0..28
    float4 rv0, rv1, rv2, rv3;
#define GLOAD(c) { \
    const float* xp = x + (size_t)(h0 + srow) * HF + K0 + (c) * 32 + scol; \
    rv0 = *(const float4*)(xp); \
    rv1 = *(const float4*)(xp + 32 * HF); \
    rv2 = *(const float4*)(xp + 64 * HF); \
    rv3 = *(const float4*)(xp + 96 * HF); }
#define SSTORE() { \
    xsT[scol+0][srow]    = rv0.x; xsT[scol+1][srow]    = rv0.y; \
    xsT[scol+2][srow]    = rv0.z; xsT[scol+3][srow]    = rv0.w; \
    xsT[scol+0][srow+32] = rv1.x; xsT[scol+1][srow+32] = rv1.y; \
    xsT[scol+2][srow+32] = rv1.z; xsT[scol+3][srow+32] = rv1.w; \
    xsT[scol+0][srow+64] = rv2.x; xsT[scol+1][srow+64] = rv2.y; \
    xsT[scol+2][srow+64] = rv2.z; xsT[scol+3][srow+64] = rv2.w; \
    xsT[scol+0][srow+96] = rv3.x; xsT[scol+1][srow+96] = rv3.y; \
    xsT[scol+2][srow+96] = rv3.z; xsT[scol+3][srow+96] = rv3.w; }

    float acc[16];
    #pragma unroll
    for (int i = 0; i < 16; ++i) acc[i] = 0.0f;
    float wA = 0.0f, wB = 0.0f;

    GLOAD(0);
    SSTORE();
    __syncthreads();
    for (int c = 0; c < 4; ++c) {
        if (c < 3) GLOAD(c + 1);              // next chunk in flight
        const int kb = K0 + c * 32;
        #pragma unroll
        for (int s = 0; s < 4; ++s) {         // sub-chunk of 8 k: batch W loads
            float2 xv[8];
            #pragma unroll
            for (int j = 0; j < 8; ++j)
                xv[j] = *(const float2*)(&xsT[s * 8 + j][2 * l]);
            const float* wp = Wc + (size_t)(kb + s * 8) * 32 + g * 8;
            #pragma unroll
            for (int j = 0; j < 8; ++j) {
                const float w0 = wp[j * 32 + 0], w1 = wp[j * 32 + 1];
                const float w2 = wp[j * 32 + 2], w3 = wp[j * 32 + 3];
                const float w4 = wp[j * 32 + 4], w5 = wp[j * 32 + 5];
                const float w6 = wp[j * 32 + 6], w7 = wp[j * 32 + 7];
                acc[0] = fmaf(xv[j].x, w0, acc[0]);  acc[8]  = fmaf(xv[j].y, w0, acc[8]);
                acc[1] = fmaf(xv[j].x, w1, acc[1]);  acc[9]  = fmaf(xv[j].y, w1, acc[9]);
                acc[2] = fmaf(xv[j].x, w2, acc[2]);  acc[10] = fmaf(xv[j].y, w2, acc[10]);
                acc[3] = fmaf(xv[j].x, w3, acc[3]);  acc[11] = fmaf(xv[j].y, w3, acc[11]);
                acc[4] = fmaf(xv[j].x, w4, acc[4]);  acc[12] = fmaf(xv[j].y, w4, acc[12]);
                acc[5] = fmaf(xv[j].x, w5, acc[5]);  acc[13] = fmaf(xv[j].y, w5, acc[13]);
                acc[6] = fmaf(xv[j].x, w6, acc[6]);  acc[14] = fmaf(xv[j].y, w6, acc[14]);
                acc[7] = fmaf(xv[j].x, w7, acc[7]);  acc[15] = fmaf(xv[j].y, w7, acc[15]);
                if (g == 3) {
                    const float wb = Wb[kb + s * 8 + j];
                    wA = fmaf(xv[j].x, wb, wA);
                    wB = fmaf(xv[j].y, wb, wB);
                }
            }
        }
        __syncthreads();                      // xsT reads done
        if (c < 3) { SSTORE(); __syncthreads(); }
    }

    // combine partials: exactly 2 commutative f32 atomics per element -> deterministic
    const int ha = h0 + 2 * l;
    #pragma unroll
    for (int c = 0; c < 8; ++c) {
        const float b = (kh == 0) ? bcrd[g * 8 + c] : 0.0f;
        atomicAdd(ws + WS_OX + (size_t)ha * DD + g * 8 + c,       acc[c] + b);
        atomicAdd(ws + WS_OX + (size_t)(ha + 1) * DD + g * 8 + c, acc[8 + c] + b);
    }
    if (g == 3) {
        const float zb = (kh == 0) ? bb[0] : 0.0f;
        atomicAdd(ws + WS_ZB + ha,     wA + zb);
        atomicAdd(ws + WS_ZB + ha + 1, wB + zb);
    }
}

// per-hit epilogue: records (dims 0..7, half-norm), beta path, noise sums
__global__ __launch_bounds__(256) void k_epi(const int* __restrict__ yi,
                                             float* __restrict__ ws) {
    const int h = blockIdx.x * 256 + threadIdx.x;
    const float* oxr = ws + WS_OX + (size_t)h * DD;
    const float4 o0 = *(const float4*)(oxr);
    const float4 o1 = *(const float4*)(oxr + 4);
    const float s8 = o0.x*o0.x + o0.y*o0.y + o0.z*o0.z + o0.w*o0.w
                   + o1.x*o1.x + o1.y*o1.y + o1.z*o1.z + o1.w*o1.w;
    float* hr = ws + WS_H12 + (size_t)h * 12;
    *(float4*)(hr)     = o0;
    *(float4*)(hr + 4) = o1;
    hr[8] = 0.5f * s8;
    const float z    = ws[WS_ZB + h];
    const float beta = 1.0f / (1.0f + expf(-z));
    const float bcv  = fminf(fmaxf(beta, 1e-4f), 0.9999f);
    const float at   = atanhf(bcv);
    hr[9]  = at * at + 0.5f;
    hr[10] = bcv;
    const int y = yi[h];
    float    nb  = (y < 0) ? bcv : 0.0f;
    unsigned cnt = (y < 0) ? 1u : 0u;
    for (int off = 32; off > 0; off >>= 1) {
        nb  += __shfl_down(nb, off);
        cnt += __shfl_down(cnt, off);
    }
    if ((threadIdx.x & 63) == 0) {
        atomicAdd(ws + WS_PART + 2, nb);
        atomicAdd((unsigned int*)(ws + WS_PART + 3), cnt);
    }
}

// fused segment argmax: pack (q_bits, NH-1-h) -> one u64 atomicMax.
__global__ __launch_bounds__(256) void k_segmax(const int* __restrict__ eh, const int* __restrict__ ei,
                                                int E, const float* __restrict__ h12,
                                                unsigned long long* __restrict__ seg) {
    int e = blockIdx.x * 256 + threadIdx.x;
    if (e < E) {
        int h = eh[e];
        float q = h12[(size_t)h * 12 + 9];
        unsigned long long pk = ((unsigned long long)__float_as_uint(q) << 32)
                              | (unsigned)(NH - 1 - h);
        atomicMax(seg + ei[e], pk);
    }
}

__global__ __launch_bounds__(256) void k_gather(float* __restrict__ ws) {
    const int k = blockIdx.x * 256 + threadIdx.x;
    unsigned long long pk = ((const unsigned long long*)(ws + WS_SEG64))[k];
    int a = NH - 1 - (int)(unsigned)(pk & 0xffffffffu);
    a = max(0, min(a, NH - 1));
    float4 v0, v1;
    float s8 = 0.0f;
    #pragma unroll
    for (int d0 = 0; d0 < DD; d0 += 4) {
        float4 v = *(const float4*)(ws + WS_OX + (size_t)a * DD + d0);
        *(float4*)(ws + WS_XA + (size_t)k * DD + d0) = v;
        if (d0 == 0) { v0 = v; s8 += v.x*v.x + v.y*v.y + v.z*v.z + v.w*v.w; }
        if (d0 == 4) { v1 = v; s8 += v.x*v.x + v.y*v.y + v.z*v.z + v.w*v.w; }
    }
    *(float4*)(ws + WS_A12 + (size_t)k * 12)     = v0;
    *(float4*)(ws + WS_A12 + (size_t)k * 12 + 4) = v1;
    ws[WS_A12 + (size_t)k * 12 + 8] = 0.5f * (s8 - 1.0f);                    // ca
    ws[WS_A12 + (size_t)k * 12 + 9] = ws[WS_H12 + (size_t)a * 12 + 9];       // qa
    float omba = 1.0f - ws[WS_H12 + (size_t)a * 12 + 10];
    for (int off = 32; off > 0; off >>= 1) omba += __shfl_down(omba, off);
    if ((threadIdx.x & 63) == 0) atomicAdd(ws + WS_PART + 4, omba);
}

__global__ __launch_bounds__(256) void k_att(const int* __restrict__ eh, const int* __restrict__ ei,
                                             int E, float* __restrict__ ws) {
    const int t = threadIdx.x;
    const int e = blockIdx.x * 256 + t;
    float c = 0.0f;
    if (e < E) {
        const int h = eh[e], k = ei[e];
        const float* a = ws + WS_OX + (size_t)h * DD;
        const float* b = ws + WS_XA + (size_t)k * DD;
        float d2 = 0.0f;
        #pragma unroll
        for (int d0 = 0; d0 < DD; d0 += 4) {
            float4 av = *(const float4*)(a + d0);
            float4 bv = *(const float4*)(b + d0);
            float dx = av.x - bv.x; d2 = fmaf(dx, dx, d2);
            float dy = av.y - bv.y; d2 = fmaf(dy, dy, d2);
            float dz = av.z - bv.z; d2 = fmaf(dz, dz, d2);
            float dw = av.w - bv.w; d2 = fmaf(dw, dw, d2);
        }
        c = ws[WS_H12 + (size_t)h * 12 + 9] * ws[WS_A12 + (size_t)k * 12 + 9] * d2;
    }
    for (int off = 32; off > 0; off >>= 1) c += __shfl_down(c, off);
    __shared__ float red[4];
    if ((t & 63) == 0) red[t >> 6] = c;
    __syncthreads();
    if (t == 0) atomicAdd(ws + WS_PART + 1, red[0] + red[1] + red[2] + red[3]);
}

// v_rep: 512 hits x 128 alphas per block; alpha records staged in LDS
// (broadcast b128 reads). Exact 8-dim lower-bound filter.
__global__ __launch_bounds__(256, 4) void k_rep(const int* __restrict__ yi,
        const float* __restrict__ a12, const float* __restrict__ h12,
        const float* __restrict__ ox, const float* __restrict__ xa,
        float* __restrict__ part) {
    __shared__ float al[128 * 12];
    const int t  = threadIdx.x;
    const int bh = blockIdx.x % 96;
    const int bk = blockIdx.x / 96;
    const int k0 = bk * 128;

    for (int i = t; i < 128 * 12; i += 256)
        al[i] = a12[(size_t)k0 * 12 + i];
    __syncthreads();

    const int h1 = bh * 512 + t;
    const int h2 = h1 + 256;
    const float4 p0  = *(const float4*)(h12 + (size_t)h1 * 12);
    const float4 p1  = *(const float4*)(h12 + (size_t)h1 * 12 + 4);
    const float2 cq1 = *(const float2*)(h12 + (size_t)h1 * 12 + 8);
    const float4 s0  = *(const float4*)(h12 + (size_t)h2 * 12);
    const float4 s1  = *(const float4*)(h12 + (size_t)h2 * 12 + 4);
    const float2 cq2 = *(const float2*)(h12 + (size_t)h2 * 12 + 8);
    const int yh1 = yi[h1], yh2 = yi[h2];
    float loc = 0.0f;

    #pragma unroll 4
    for (int r = 0; r < 128; ++r) {
        const float4 b0  = *(const float4*)(al + r * 12);
        const float4 b1  = *(const float4*)(al + r * 12 + 4);
        const float2 bcq = *(const float2*)(al + r * 12 + 8);
        float acc1 = -cq1.x - bcq.x;
        acc1 = fmaf(p0.x, b0.x, acc1);
        acc1 = fmaf(p0.y, b0.y, acc1);
        acc1 = fmaf(p0.z, b0.z, acc1);
        acc1 = fmaf(p0.w, b0.w, acc1);
        acc1 = fmaf(p1.x, b1.x, acc1);
        acc1 = fmaf(p1.y, b1.y, acc1);
        acc1 = fmaf(p1.z, b1.z, acc1);
        acc1 = fmaf(p1.w, b1.w, acc1);
        float acc2 = -cq2.x - bcq.x;
        acc2 = fmaf(s0.x, b0.x, acc2);
        acc2 = fmaf(s0.y, b0.y, acc2);
        acc2 = fmaf(s0.z, b0.z, acc2);
        acc2 = fmaf(s0.w, b0.w, acc2);
        acc2 = fmaf(s1.x, b1.x, acc2);
        acc2 = fmaf(s1.y, b1.y, acc2);
        acc2 = fmaf(s1.z, b1.z, acc2);
        acc2 = fmaf(s1.w, b1.w, acc2);
        if (acc1 > 0.0f) {          // rare: d2 over first 8 dims < 1
            const int kg = k0 + r;
            if (yh1 != kg) {
                float d2 = 1.0f - 2.0f * acc1;
                const float* hp  = ox + (size_t)h1 * DD;
                const float* apf = xa + (size_t)kg * DD;
                #pragma unroll
                for (int d = 8; d < DD; d += 4) {
                    float4 av = *(const float4*)(hp + d);
                    float4 bv = *(const float4*)(apf + d);
                    float dx = av.x - bv.x; d2 = fmaf(dx, dx, d2);
                    float dy = av.y - bv.y; d2 = fmaf(dy, dy, d2);
                    float dz = av.z - bv.z; d2 = fmaf(dz, dz, d2);
                    float dw = av.w - bv.w; d2 = fmaf(dw, dw, d2);
                }
                float dist = sqrtf(fmaxf(d2, 0.0f) + 1e-12f);
                float hin  = 1.0f - dist;
                if (hin > 0.0f) loc += cq1.y * bcq.y * hin;
            }
        }
        if (acc2 > 0.0f) {
            const int kg = k0 + r;
            if (yh2 != kg) {
                float d2 = 1.0f - 2.0f * acc2;
                const float* hp  = ox + (size_t)h2 * DD;
                const float* apf = xa + (size_t)kg * DD;
                #pragma unroll
                for (int d = 8; d < DD; d += 4) {
                    float4 av = *(const float4*)(hp + d);
                    float4 bv = *(const float4*)(apf + d);
                    float dx = av.x - bv.x; d2 = fmaf(dx, dx, d2);
                    float dy = av.y - bv.y; d2 = fmaf(dy, dy, d2);
                    float dz = av.z - bv.z; d2 = fmaf(dz, dz, d2);
                    float dw = av.w - bv.w; d2 = fmaf(dw, dw, d2);
                }
                float dist = sqrtf(fmaxf(d2, 0.0f) + 1e-12f);
                float hin  = 1.0f - dist;
                if (hin > 0.0f) loc += cq2.y * bcq.y * hin;
            }
        }
    }
    for (int off = 32; off > 0; off >>= 1) loc += __shfl_down(loc, off);
    __shared__ float red[4];
    if ((t & 63) == 0) red[t >> 6] = loc;
    __syncthreads();
    if (t == 0) atomicAdd(part + 0, red[0] + red[1] + red[2] + red[3]);
}

__global__ void k_final(const float* __restrict__ temp, float* __restrict__ ws,
                        float* __restrict__ out) {
    float vrep  = ws[WS_PART + 0];
    float vatt  = ws[WS_PART + 1];
    float nsum  = ws[WS_PART + 2];
    unsigned nn = *(const unsigned int*)(ws + WS_PART + 3);
    float somba = ws[WS_PART + 4];
    float lb = somba * (1.0f / (float)KI) + nsum / (float)(nn < 1u ? 1u : nn);
    float lv = (vatt + vrep) / (float)NH;
    float tv = temp[0];
    out[0] = (lb + lv) * expf(-tv) + tv;
}

extern "C" void kernel_launch(void* const* d_in, const int* in_sizes, int n_in,
                              void* d_out, int out_size, void* d_ws, size_t ws_size,
                              hipStream_t stream) {
    const float* x    = (const float*)d_in[0];
    const float* Wb   = (const float*)d_in[1];
    const float* bb   = (const float*)d_in[2];
    const float* Wc   = (const float*)d_in[3];
    const float* bcrd = (const float*)d_in[4];
    const float* temp = (const float*)d_in[5];
    const int*   yi   = (const int*)d_in[6];
    const int*   ep   = (const int*)d_in[8];
    const int E = in_sizes[8] / 2;
    const int* eh = ep;
    const int* ei = ep + E;
    float* ws  = (float*)d_ws;
    float* out = (float*)d_out;

    k_init<<<1536, 256, 0, stream>>>(ws);
    k_gemm<<<(NH / 128) * 2, 256, 0, stream>>>(x, Wb, bb, Wc, bcrd, ws);
    k_epi<<<NH / 256, 256, 0, stream>>>(yi, ws);
    const int eb = (E + 255) / 256;
    k_segmax<<<eb, 256, 0, stream>>>(eh, ei, E, ws + WS_H12,
                                     (unsigned long long*)(ws + WS_SEG64));
    k_gather<<<KI / 256, 256, 0, stream>>>(ws);
    k_att<<<eb, 256, 0, stream>>>(eh, ei, E, ws);
    k_rep<<<96 * 8, 256, 0, stream>>>(yi, ws + WS_A12, ws + WS_H12,
                                      ws + WS_OX, ws + WS_XA, ws);
    k_final<<<1, 1, 0, stream>>>(temp, ws, out);
}

// Round 6
// 159.194 us; speedup vs baseline: 1.6390x; 1.6390x over previous
//
#include <hip/hip_runtime.h>
#include <math.h>

#define NH 49152
#define KI 1024
#define DD 32
#define HF 256

// float-index layout in ws
#define WS_PART  0                    // [0]=vrep [1]=vatt [2]=noise_sum [3]=n_noise(u32) [4]=sum(1-beta_a)
#define WS_SEG64 8                    // KI u64 packed (q_bits<<32 | NH-1-h)
#define WS_A12   (WS_SEG64 + 2*KI)    // KI*12: d0..7, ca, qa, pad2
#define WS_H12   (WS_A12 + 12*KI)     // NH*12: d0..7, ch, q, bc, pad
#define WS_XA    (WS_H12 + 12*NH)     // KI*DD full alpha coords
#define WS_OX    (WS_XA + KI*DD)      // NH*DD

__global__ void k_init(float* __restrict__ ws) {
    int i = blockIdx.x * blockDim.x + threadIdx.x;
    if (i < 512) *(float4*)(ws + WS_SEG64 + (size_t)i * 4) = make_float4(0.f, 0.f, 0.f, 0.f);
    if (i < 8) ws[WS_PART + i] = 0.0f;
}

// GEMM: 128 hits x 33 cols per block, grid 384, 2 blocks/CU (LDS 71.7KB).
// Lane tile 4 hits x 4 cols: per kk only 2 LDS instr (x b128 2-way-shared,
// W b128 16-way-broadcast) per 16-20 FMA instr -> LDS pipe no longer the limit.
// x staged k-major (in-reg 4x4 transpose), double-buffered, 1 barrier/chunk.
__global__ __launch_bounds__(256, 2) void k_gemm(
        const float* __restrict__ x, const float* __restrict__ Wb,
        const float* __restrict__ bb, const float* __restrict__ Wc,
        const float* __restrict__ bcrd, const int* __restrict__ yi,
        float* __restrict__ ws) {
    __shared__ float wl[256 * 36];    // W rows padded to 36 (16B-aligned b128)
    __shared__ float wbl[256];        // beta weight column
    __shared__ float xsT[2][32][132]; // [k within chunk][hit], k-major
    const int t  = threadIdx.x;
    const int w  = t >> 6;
    const int hh = w >> 1;            // hit half (0/1)
    const int cg = w & 1;             // col group (16 cols)
    const int l  = t & 63;
    const int q  = l >> 2;            // hit quad 0..15
    const int cs = l & 3;             // col sub-group 0..3
    const int h0 = blockIdx.x * 128;

    {   // stage full W once: thread t stages k-row t
        const float* wr = Wc + t * 32;
        float* dst = wl + t * 36;
        #pragma unroll
        for (int j = 0; j < 8; ++j)
            *(float4*)(dst + j * 4) = *(const float4*)(wr + j * 4);
        wbl[t] = Wb[t];
    }

    const int sg = t >> 3;            // staging hit group 0..31 (4 hits)
    const int kq = t & 7;             // staging k quad 0..7
    const float* xbase = x + (size_t)(h0 + 4 * sg) * HF + kq * 4;
    float4 v0, v1, v2, v3;
#define GLOAD(c) { \
    const float* xp = xbase + (c) * 32; \
    v0 = *(const float4*)(xp); \
    v1 = *(const float4*)(xp + HF); \
    v2 = *(const float4*)(xp + 2 * HF); \
    v3 = *(const float4*)(xp + 3 * HF); }
#define SSTORE(b) { \
    *(float4*)(&xsT[b][kq * 4 + 0][sg * 4]) = make_float4(v0.x, v1.x, v2.x, v3.x); \
    *(float4*)(&xsT[b][kq * 4 + 1][sg * 4]) = make_float4(v0.y, v1.y, v2.y, v3.y); \
    *(float4*)(&xsT[b][kq * 4 + 2][sg * 4]) = make_float4(v0.z, v1.z, v2.z, v3.z); \
    *(float4*)(&xsT[b][kq * 4 + 3][sg * 4]) = make_float4(v0.w, v1.w, v2.w, v3.w); }

    float acc[4][4];
    #pragma unroll
    for (int i = 0; i < 4; ++i)
        #pragma unroll
        for (int j = 0; j < 4; ++j) acc[i][j] = 0.0f;
    float c32[4] = {0.f, 0.f, 0.f, 0.f};

    GLOAD(0);
    SSTORE(0);
    __syncthreads();
    for (int c = 0; c < 8; ++c) {
        if (c < 7) GLOAD(c + 1);              // in flight across whole compute
        const int kb = c * 32;
        const float (*xb)[132] = xsT[c & 1];
        #pragma unroll
        for (int k4 = 0; k4 < 8; ++k4) {
            const float4 wb4 = *(const float4*)(wbl + kb + k4 * 4);
            #pragma unroll
            for (int j4 = 0; j4 < 4; ++j4) {
                const int kk = k4 * 4 + j4;
                const float4 xv = *(const float4*)(&xb[kk][hh * 64 + q * 4]);
                const float4 wv = *(const float4*)(wl + (size_t)(kb + kk) * 36 + cg * 16 + cs * 4);
                acc[0][0] = fmaf(xv.x, wv.x, acc[0][0]);
                acc[0][1] = fmaf(xv.x, wv.y, acc[0][1]);
                acc[0][2] = fmaf(xv.x, wv.z, acc[0][2]);
                acc[0][3] = fmaf(xv.x, wv.w, acc[0][3]);
                acc[1][0] = fmaf(xv.y, wv.x, acc[1][0]);
                acc[1][1] = fmaf(xv.y, wv.y, acc[1][1]);
                acc[1][2] = fmaf(xv.y, wv.z, acc[1][2]);
                acc[1][3] = fmaf(xv.y, wv.w, acc[1][3]);
                acc[2][0] = fmaf(xv.z, wv.x, acc[2][0]);
                acc[2][1] = fmaf(xv.z, wv.y, acc[2][1]);
                acc[2][2] = fmaf(xv.z, wv.z, acc[2][2]);
                acc[2][3] = fmaf(xv.z, wv.w, acc[2][3]);
                acc[3][0] = fmaf(xv.w, wv.x, acc[3][0]);
                acc[3][1] = fmaf(xv.w, wv.y, acc[3][1]);
                acc[3][2] = fmaf(xv.w, wv.z, acc[3][2]);
                acc[3][3] = fmaf(xv.w, wv.w, acc[3][3]);
                if (cg == 0) {                 // wave-uniform: only cg0 waves
                    const float wbv = (j4 == 0) ? wb4.x : (j4 == 1) ? wb4.y
                                    : (j4 == 2) ? wb4.z : wb4.w;
                    c32[0] = fmaf(xv.x, wbv, c32[0]);
                    c32[1] = fmaf(xv.y, wbv, c32[1]);
                    c32[2] = fmaf(xv.z, wbv, c32[2]);
                    c32[3] = fmaf(xv.w, wbv, c32[3]);
                }
            }
        }
        if (c < 7) SSTORE((c + 1) & 1);       // other buffer; vmcnt wait lands here
        __syncthreads();                       // buffer (c+1)&1 published
    }

    const int col0 = cg * 16 + cs * 4;
    const float4 bias = *(const float4*)(bcrd + col0);
    const int hb = h0 + hh * 64 + q * 4;
    float4 o[4];
    #pragma unroll
    for (int i = 0; i < 4; ++i) {
        o[i].x = acc[i][0] + bias.x;
        o[i].y = acc[i][1] + bias.y;
        o[i].z = acc[i][2] + bias.z;
        o[i].w = acc[i][3] + bias.w;
        *(float4*)(ws + WS_OX + (size_t)(hb + i) * DD + col0) = o[i];
    }

    if (cg == 0) {
        // filter records: cs0 holds dims 0-3, cs1 dims 4-7; s8 via pair shuffle
        float s8[4];
        #pragma unroll
        for (int i = 0; i < 4; ++i) {
            float sq = o[i].x * o[i].x + o[i].y * o[i].y
                     + o[i].z * o[i].z + o[i].w * o[i].w;
            s8[i] = sq + __shfl_xor(sq, 1);
        }
        if (cs < 2) {
            #pragma unroll
            for (int i = 0; i < 4; ++i) {
                float* hr = ws + WS_H12 + (size_t)(hb + i) * 12;
                *(float4*)(hr + cs * 4) = o[i];
                if (cs == 0) hr[8] = 0.5f * s8[i];
            }
        }
        float nb = 0.0f; unsigned cnt = 0u;
        if (cs == 0) {
            const float bb0 = bb[0];
            #pragma unroll
            for (int i = 0; i < 4; ++i) {
                const float z    = c32[i] + bb0;
                const float beta = 1.0f / (1.0f + expf(-z));
                const float bcv  = fminf(fmaxf(beta, 1e-4f), 0.9999f);
                const float at   = atanhf(bcv);
                float* hr = ws + WS_H12 + (size_t)(hb + i) * 12;
                hr[9]  = at * at + 0.5f;
                hr[10] = bcv;
                const int y = yi[hb + i];
                if (y < 0) { nb += bcv; cnt += 1u; }
            }
        }
        for (int off = 32; off > 0; off >>= 1) {
            nb  += __shfl_down(nb, off);
            cnt += __shfl_down(cnt, off);
        }
        if (l == 0) {
            atomicAdd(ws + WS_PART + 2, nb);
            atomicAdd((unsigned int*)(ws + WS_PART + 3), cnt);
        }
    }
}

// fused segment argmax: pack (q_bits, NH-1-h) -> one u64 atomicMax.
__global__ __launch_bounds__(256) void k_segmax(const int* __restrict__ eh, const int* __restrict__ ei,
                                                int E, const float* __restrict__ h12,
                                                unsigned long long* __restrict__ seg) {
    int e = blockIdx.x * 256 + threadIdx.x;
    if (e < E) {
        int h = eh[e];
        float q = h12[(size_t)h * 12 + 9];
        unsigned long long pk = ((unsigned long long)__float_as_uint(q) << 32)
                              | (unsigned)(NH - 1 - h);
        atomicMax(seg + ei[e], pk);
    }
}

__global__ __launch_bounds__(256) void k_gather(float* __restrict__ ws) {
    const int k = blockIdx.x * 256 + threadIdx.x;
    unsigned long long pk = ((const unsigned long long*)(ws + WS_SEG64))[k];
    int a = NH - 1 - (int)(unsigned)(pk & 0xffffffffu);
    a = max(0, min(a, NH - 1));
    float4 v0, v1;
    float s8 = 0.0f;
    #pragma unroll
    for (int d0 = 0; d0 < DD; d0 += 4) {
        float4 v = *(const float4*)(ws + WS_OX + (size_t)a * DD + d0);
        *(float4*)(ws + WS_XA + (size_t)k * DD + d0) = v;
        if (d0 == 0) { v0 = v; s8 += v.x*v.x + v.y*v.y + v.z*v.z + v.w*v.w; }
        if (d0 == 4) { v1 = v; s8 += v.x*v.x + v.y*v.y + v.z*v.z + v.w*v.w; }
    }
    *(float4*)(ws + WS_A12 + (size_t)k * 12)     = v0;
    *(float4*)(ws + WS_A12 + (size_t)k * 12 + 4) = v1;
    ws[WS_A12 + (size_t)k * 12 + 8] = 0.5f * (s8 - 1.0f);                    // ca
    ws[WS_A12 + (size_t)k * 12 + 9] = ws[WS_H12 + (size_t)a * 12 + 9];       // qa
    float omba = 1.0f - ws[WS_H12 + (size_t)a * 12 + 10];
    for (int off = 32; off > 0; off >>= 1) omba += __shfl_down(omba, off);
    if ((threadIdx.x & 63) == 0) atomicAdd(ws + WS_PART + 4, omba);
}

__global__ __launch_bounds__(256) void k_att(const int* __restrict__ eh, const int* __restrict__ ei,
                                             int E, float* __restrict__ ws) {
    const int t = threadIdx.x;
    const int e = blockIdx.x * 256 + t;
    float c = 0.0f;
    if (e < E) {
        const int h = eh[e], k = ei[e];
        const float* a = ws + WS_OX + (size_t)h * DD;
        const float* b = ws + WS_XA + (size_t)k * DD;
        float d2 = 0.0f;
        #pragma unroll
        for (int d0 = 0; d0 < DD; d0 += 4) {
            float4 av = *(const float4*)(a + d0);
            float4 bv = *(const float4*)(b + d0);
            float dx = av.x - bv.x; d2 = fmaf(dx, dx, d2);
            float dy = av.y - bv.y; d2 = fmaf(dy, dy, d2);
            float dz = av.z - bv.z; d2 = fmaf(dz, dz, d2);
            float dw = av.w - bv.w; d2 = fmaf(dw, dw, d2);
        }
        c = ws[WS_H12 + (size_t)h * 12 + 9] * ws[WS_A12 + (size_t)k * 12 + 9] * d2;
    }
    for (int off = 32; off > 0; off >>= 1) c += __shfl_down(c, off);
    __shared__ float red[4];
    if ((t & 63) == 0) red[t >> 6] = c;
    __syncthreads();
    if (t == 0) atomicAdd(ws + WS_PART + 1, red[0] + red[1] + red[2] + red[3]);
}

// v_rep: 512 hits x 128 alphas per block; alpha records staged in LDS
// (broadcast b128 reads). Exact 8-dim lower-bound filter.
__global__ __launch_bounds__(256, 4) void k_rep(const int* __restrict__ yi,
        const float* __restrict__ a12, const float* __restrict__ h12,
        const float* __restrict__ ox, const float* __restrict__ xa,
        float* __restrict__ part) {
    __shared__ float al[128 * 12];
    const int t  = threadIdx.x;
    const int bh = blockIdx.x % 96;
    const int bk = blockIdx.x / 96;
    const int k0 = bk * 128;

    for (int i = t; i < 128 * 12; i += 256)
        al[i] = a12[(size_t)k0 * 12 + i];
    __syncthreads();

    const int h1 = bh * 512 + t;
    const int h2 = h1 + 256;
    const float4 p0  = *(const float4*)(h12 + (size_t)h1 * 12);
    const float4 p1  = *(const float4*)(h12 + (size_t)h1 * 12 + 4);
    const float2 cq1 = *(const float2*)(h12 + (size_t)h1 * 12 + 8);
    const float4 s0  = *(const float4*)(h12 + (size_t)h2 * 12);
    const float4 s1  = *(const float4*)(h12 + (size_t)h2 * 12 + 4);
    const float2 cq2 = *(const float2*)(h12 + (size_t)h2 * 12 + 8);
    const int yh1 = yi[h1], yh2 = yi[h2];
    float loc = 0.0f;

    #pragma unroll 4
    for (int r = 0; r < 128; ++r) {
        const float4 b0  = *(const float4*)(al + r * 12);
        const float4 b1  = *(const float4*)(al + r * 12 + 4);
        const float2 bcq = *(const float2*)(al + r * 12 + 8);
        float acc1 = -cq1.x - bcq.x;
        acc1 = fmaf(p0.x, b0.x, acc1);
        acc1 = fmaf(p0.y, b0.y, acc1);
        acc1 = fmaf(p0.z, b0.z, acc1);
        acc1 = fmaf(p0.w, b0.w, acc1);
        acc1 = fmaf(p1.x, b1.x, acc1);
        acc1 = fmaf(p1.y, b1.y, acc1);
        acc1 = fmaf(p1.z, b1.z, acc1);
        acc1 = fmaf(p1.w, b1.w, acc1);
        float acc2 = -cq2.x - bcq.x;
        acc2 = fmaf(s0.x, b0.x, acc2);
        acc2 = fmaf(s0.y, b0.y, acc2);
        acc2 = fmaf(s0.z, b0.z, acc2);
        acc2 = fmaf(s0.w, b0.w, acc2);
        acc2 = fmaf(s1.x, b1.x, acc2);
        acc2 = fmaf(s1.y, b1.y, acc2);
        acc2 = fmaf(s1.z, b1.z, acc2);
        acc2 = fmaf(s1.w, b1.w, acc2);
        if (acc1 > 0.0f) {          // rare: d2 over first 8 dims < 1
            const int kg = k0 + r;
            if (yh1 != kg) {
                float d2 = 1.0f - 2.0f * acc1;
                const float* hp  = ox + (size_t)h1 * DD;
                const float* apf = xa + (size_t)kg * DD;
                #pragma unroll
                for (int d = 8; d < DD; d += 4) {
                    float4 av = *(const float4*)(hp + d);
                    float4 bv = *(const float4*)(apf + d);
                    float dx = av.x - bv.x; d2 = fmaf(dx, dx, d2);
                    float dy = av.y - bv.y; d2 = fmaf(dy, dy, d2);
                    float dz = av.z - bv.z; d2 = fmaf(dz, dz, d2);
                    float dw = av.w - bv.w; d2 = fmaf(dw, dw, d2);
                }
                float dist = sqrtf(fmaxf(d2, 0.0f) + 1e-12f);
                float hin  = 1.0f - dist;
                if (hin > 0.0f) loc += cq1.y * bcq.y * hin;
            }
        }
        if (acc2 > 0.0f) {
            const int kg = k0 + r;
            if (yh2 != kg) {
                float d2 = 1.0f - 2.0f * acc2;
                const float* hp  = ox + (size_t)h2 * DD;
                const float* apf = xa + (size_t)kg * DD;
                #pragma unroll
                for (int d = 8; d < DD; d += 4) {
                    float4 av = *(const float4*)(hp + d);
                    float4 bv = *(const float4*)(apf + d);
                    float dx = av.x - bv.x; d2 = fmaf(dx, dx, d2);
                    float dy = av.y - bv.y; d2 = fmaf(dy, dy, d2);
                    float dz = av.z - bv.z; d2 = fmaf(dz, dz, d2);
                    float dw = av.w - bv.w; d2 = fmaf(dw, dw, d2);
                }
                float dist = sqrtf(fmaxf(d2, 0.0f) + 1e-12f);
                float hin  = 1.0f - dist;
                if (hin > 0.0f) loc += cq2.y * bcq.y * hin;
            }
        }
    }
    for (int off = 32; off > 0; off >>= 1) loc += __shfl_down(loc, off);
    __shared__ float red[4];
    if ((t & 63) == 0) red[t >> 6] = loc;
    __syncthreads();
    if (t == 0) atomicAdd(part + 0, red[0] + red[1] + red[2] + red[3]);
}

__global__ void k_final(const float* __restrict__ temp, float* __restrict__ ws,
                        float* __restrict__ out) {
    float vrep  = ws[WS_PART + 0];
    float vatt  = ws[WS_PART + 1];
    float nsum  = ws[WS_PART + 2];
    unsigned nn = *(const unsigned int*)(ws + WS_PART + 3);
    float somba = ws[WS_PART + 4];
    float lb = somba * (1.0f / (float)KI) + nsum / (float)(nn < 1u ? 1u : nn);
    float lv = (vatt + vrep) / (float)NH;
    float tv = temp[0];
    out[0] = (lb + lv) * expf(-tv) + tv;
}

extern "C" void kernel_launch(void* const* d_in, const int* in_sizes, int n_in,
                              void* d_out, int out_size, void* d_ws, size_t ws_size,
                              hipStream_t stream) {
    const float* x    = (const float*)d_in[0];
    const float* Wb   = (const float*)d_in[1];
    const float* bb   = (const float*)d_in[2];
    const float* Wc   = (const float*)d_in[3];
    const float* bcrd = (const float*)d_in[4];
    const float* temp = (const float*)d_in[5];
    const int*   yi   = (const int*)d_in[6];
    const int*   ep   = (const int*)d_in[8];
    const int E = in_sizes[8] / 2;
    const int* eh = ep;
    const int* ei = ep + E;
    float* ws  = (float*)d_ws;
    float* out = (float*)d_out;

    k_init<<<4, 256, 0, stream>>>(ws);
    k_gemm<<<NH / 128, 256, 0, stream>>>(x, Wb, bb, Wc, bcrd, yi, ws);
    const int eb = (E + 255) / 256;
    k_segmax<<<eb, 256, 0, stream>>>(eh, ei, E, ws + WS_H12,
                                     (unsigned long long*)(ws + WS_SEG64));
    k_gather<<<KI / 256, 256, 0, stream>>>(ws);
    k_att<<<eb, 256, 0, stream>>>(eh, ei, E, ws);
    k_rep<<<96 * 8, 256, 0, stream>>>(yi, ws + WS_A12, ws + WS_H12,
                                      ws + WS_OX, ws + WS_XA, ws);
    k_final<<<1, 1, 0, stream>>>(temp, ws, out);
}

// Round 7
// 122.850 us; speedup vs baseline: 2.1239x; 1.2958x over previous
//
#include <hip/hip_runtime.h>
#include <math.h>

#define NH 49152
#define KI 1024
#define DD 32
#define HF 256

// float-index layout in ws
#define WS_PART  0                    // [0]=vrep [1]=vatt [2]=noise_sum [3]=n_noise(u32) [4]=sum(1-beta_a)
#define WS_SEG64 8                    // KI u64 packed (q_bits<<32 | NH-1-h)
#define WS_W2    2064                 // 128 k-pairs x 72: [k2][col][j], col 32 = Wb
#define WS_A12   (WS_W2 + 128*72)     // KI*12: d0..7, ca, qa, pad2
#define WS_H12   (WS_A12 + 12*KI)     // NH*12: d0..7, ch, q, bc, pad
#define WS_XA    (WS_H12 + 12*NH)     // KI*DD full alpha coords
#define WS_OX    (WS_XA + KI*DD)      // NH*DD

// pack W k-pair-blocked (W2[k2*72 + col*2 + j]) + zero seg64/parts
__global__ __launch_bounds__(256) void k_prep(const float* __restrict__ Wc,
                                              const float* __restrict__ Wb,
                                              float* __restrict__ ws) {
    const int i = blockIdx.x * 256 + threadIdx.x;
    if (i < 128 * 66) {
        const int k2 = i / 66, r = i - k2 * 66;
        const int col = r >> 1, j = r & 1;
        const float v = (col < 32) ? Wc[(2 * k2 + j) * 32 + col] : Wb[2 * k2 + j];
        ws[WS_W2 + k2 * 72 + col * 2 + j] = v;
    }
    if (i < 512) *(float4*)(ws + WS_SEG64 + (size_t)i * 4) = make_float4(0.f, 0.f, 0.f, 0.f);
    if (i < 8) ws[WS_PART + i] = 0.0f;
}

// GEMM: 64 hits x 33 cols per block, grid 768 (exactly 3 blocks/CU, 12 waves).
// W via wave-uniform s_load (SGPR broadcast operand, zero LDS/VALU cost);
// x via per-lane ds_read_b64 from pair-major LDS (conflict-free).
__global__ __launch_bounds__(256, 3) void k_gemm(
        const float* __restrict__ x, const float* __restrict__ bb,
        const float* __restrict__ bcrd, const int* __restrict__ yi,
        float* __restrict__ ws) {
    __shared__ float xsT[2][16][132];  // [k-pair within chunk][2*hit], pad 132
    const int t  = threadIdx.x;
    const int g  = __builtin_amdgcn_readfirstlane(t >> 6);   // wave = col group
    const int l  = t & 63;                                   // lane = hit
    const int h0 = blockIdx.x * 64;
    const float* __restrict__ w2 = ws + WS_W2;

    const int srow = t >> 2;          // staging hit 0..63
    const int sk4  = (t & 3) * 4;     // staging k-pair base 0..12
    float4 u0, u1;
#define GLOAD(c) { \
    const float* xp = x + (size_t)(h0 + srow) * HF + (c) * 32 + (t & 3) * 8; \
    u0 = *(const float4*)(xp); \
    u1 = *(const float4*)(xp + 4); }
#define SSTORE(b) { \
    *(float2*)(&xsT[b][sk4 + 0][2 * srow]) = make_float2(u0.x, u0.y); \
    *(float2*)(&xsT[b][sk4 + 1][2 * srow]) = make_float2(u0.z, u0.w); \
    *(float2*)(&xsT[b][sk4 + 2][2 * srow]) = make_float2(u1.x, u1.y); \
    *(float2*)(&xsT[b][sk4 + 3][2 * srow]) = make_float2(u1.z, u1.w); }

    float acc[8];
    #pragma unroll
    for (int i = 0; i < 8; ++i) acc[i] = 0.0f;
    float c32 = 0.0f;

    GLOAD(0);
    SSTORE(0);
    __syncthreads();
    for (int c = 0; c < 8; ++c) {
        if (c < 7) GLOAD(c + 1);              // HBM latency hides under compute
        const float (*xb)[132] = xsT[c & 1];
        #pragma unroll
        for (int p = 0; p < 16; ++p) {        // k-pair
            const float2 xf = *(const float2*)(&xb[p][2 * l]);
            const float* wp = w2 + (size_t)(c * 16 + p) * 72 + g * 16;  // uniform -> s_load
            #pragma unroll
            for (int c8 = 0; c8 < 8; ++c8) {
                acc[c8] = fmaf(xf.x, wp[c8 * 2],     acc[c8]);
                acc[c8] = fmaf(xf.y, wp[c8 * 2 + 1], acc[c8]);
            }
            if (g == 0) {                      // beta col (uniform branch)
                c32 = fmaf(xf.x, wp[64], c32);
                c32 = fmaf(xf.y, wp[65], c32);
            }
        }
        __syncthreads();                       // all reads of buf c&1 done
        if (c < 7) { SSTORE((c + 1) & 1); __syncthreads(); }
    }

    const int h = h0 + l;
    const float4 bc0 = *(const float4*)(bcrd + g * 8);
    const float4 bc1 = *(const float4*)(bcrd + g * 8 + 4);
    const float4 O0 = {acc[0] + bc0.x, acc[1] + bc0.y, acc[2] + bc0.z, acc[3] + bc0.w};
    const float4 O1 = {acc[4] + bc1.x, acc[5] + bc1.y, acc[6] + bc1.z, acc[7] + bc1.w};
    *(float4*)(ws + WS_OX + (size_t)h * DD + g * 8)     = O0;
    *(float4*)(ws + WS_OX + (size_t)h * DD + g * 8 + 4) = O1;

    if (g == 0) {   // cols 0-7 = filter dims; this wave owns the full record
        const float s8 = O0.x*O0.x + O0.y*O0.y + O0.z*O0.z + O0.w*O0.w
                       + O1.x*O1.x + O1.y*O1.y + O1.z*O1.z + O1.w*O1.w;
        float* hr = ws + WS_H12 + (size_t)h * 12;
        *(float4*)(hr)     = O0;
        *(float4*)(hr + 4) = O1;
        hr[8] = 0.5f * s8;
        const float z    = c32 + bb[0];
        const float beta = 1.0f / (1.0f + expf(-z));
        const float bcv  = fminf(fmaxf(beta, 1e-4f), 0.9999f);
        const float at   = atanhf(bcv);
        hr[9]  = at * at + 0.5f;
        hr[10] = bcv;
        const int y = yi[h];
        float    nb  = (y < 0) ? bcv : 0.0f;
        unsigned cnt = (y < 0) ? 1u : 0u;
        for (int off = 32; off > 0; off >>= 1) {
            nb  += __shfl_down(nb, off);
            cnt += __shfl_down(cnt, off);
        }
        if (l == 0) {
            atomicAdd(ws + WS_PART + 2, nb);
            atomicAdd((unsigned int*)(ws + WS_PART + 3), cnt);
        }
    }
}

// fused segment argmax: pack (q_bits, NH-1-h) -> one u64 atomicMax.
__global__ __launch_bounds__(256) void k_segmax(const int* __restrict__ eh, const int* __restrict__ ei,
                                                int E, const float* __restrict__ h12,
                                                unsigned long long* __restrict__ seg) {
    int e = blockIdx.x * 256 + threadIdx.x;
    if (e < E) {
        int h = eh[e];
        float q = h12[(size_t)h * 12 + 9];
        unsigned long long pk = ((unsigned long long)__float_as_uint(q) << 32)
                              | (unsigned)(NH - 1 - h);
        atomicMax(seg + ei[e], pk);
    }
}

__global__ __launch_bounds__(256) void k_gather(float* __restrict__ ws) {
    const int k = blockIdx.x * 256 + threadIdx.x;
    unsigned long long pk = ((const unsigned long long*)(ws + WS_SEG64))[k];
    int a = NH - 1 - (int)(unsigned)(pk & 0xffffffffu);
    a = max(0, min(a, NH - 1));
    float4 v0, v1;
    float s8 = 0.0f;
    #pragma unroll
    for (int d0 = 0; d0 < DD; d0 += 4) {
        float4 v = *(const float4*)(ws + WS_OX + (size_t)a * DD + d0);
        *(float4*)(ws + WS_XA + (size_t)k * DD + d0) = v;
        if (d0 == 0) { v0 = v; s8 += v.x*v.x + v.y*v.y + v.z*v.z + v.w*v.w; }
        if (d0 == 4) { v1 = v; s8 += v.x*v.x + v.y*v.y + v.z*v.z + v.w*v.w; }
    }
    *(float4*)(ws + WS_A12 + (size_t)k * 12)     = v0;
    *(float4*)(ws + WS_A12 + (size_t)k * 12 + 4) = v1;
    ws[WS_A12 + (size_t)k * 12 + 8] = 0.5f * (s8 - 1.0f);                    // ca
    ws[WS_A12 + (size_t)k * 12 + 9] = ws[WS_H12 + (size_t)a * 12 + 9];       // qa
    float omba = 1.0f - ws[WS_H12 + (size_t)a * 12 + 10];
    for (int off = 32; off > 0; off >>= 1) omba += __shfl_down(omba, off);
    if ((threadIdx.x & 63) == 0) atomicAdd(ws + WS_PART + 4, omba);
}

__global__ __launch_bounds__(256) void k_att(const int* __restrict__ eh, const int* __restrict__ ei,
                                             int E, float* __restrict__ ws) {
    const int t = threadIdx.x;
    const int e = blockIdx.x * 256 + t;
    float c = 0.0f;
    if (e < E) {
        const int h = eh[e], k = ei[e];
        const float* a = ws + WS_OX + (size_t)h * DD;
        const float* b = ws + WS_XA + (size_t)k * DD;
        float d2 = 0.0f;
        #pragma unroll
        for (int d0 = 0; d0 < DD; d0 += 4) {
            float4 av = *(const float4*)(a + d0);
            float4 bv = *(const float4*)(b + d0);
            float dx = av.x - bv.x; d2 = fmaf(dx, dx, d2);
            float dy = av.y - bv.y; d2 = fmaf(dy, dy, d2);
            float dz = av.z - bv.z; d2 = fmaf(dz, dz, d2);
            float dw = av.w - bv.w; d2 = fmaf(dw, dw, d2);
        }
        c = ws[WS_H12 + (size_t)h * 12 + 9] * ws[WS_A12 + (size_t)k * 12 + 9] * d2;
    }
    for (int off = 32; off > 0; off >>= 1) c += __shfl_down(c, off);
    __shared__ float red[4];
    if ((t & 63) == 0) red[t >> 6] = c;
    __syncthreads();
    if (t == 0) atomicAdd(ws + WS_PART + 1, red[0] + red[1] + red[2] + red[3]);
}

// v_rep: 512 hits x 128 alphas per block; alpha records staged in LDS.
// Exact 8-dim lower-bound filter.
__global__ __launch_bounds__(256, 4) void k_rep(const int* __restrict__ yi,
        const float* __restrict__ a12, const float* __restrict__ h12,
        const float* __restrict__ ox, const float* __restrict__ xa,
        float* __restrict__ part) {
    __shared__ float al[128 * 12];
    const int t  = threadIdx.x;
    const int bh = blockIdx.x % 96;
    const int bk = blockIdx.x / 96;
    const int k0 = bk * 128;

    for (int i = t; i < 128 * 12; i += 256)
        al[i] = a12[(size_t)k0 * 12 + i];
    __syncthreads();

    const int h1 = bh * 512 + t;
    const int h2 = h1 + 256;
    const float4 p0  = *(const float4*)(h12 + (size_t)h1 * 12);
    const float4 p1  = *(const float4*)(h12 + (size_t)h1 * 12 + 4);
    const float2 cq1 = *(const float2*)(h12 + (size_t)h1 * 12 + 8);
    const float4 s0  = *(const float4*)(h12 + (size_t)h2 * 12);
    const float4 s1  = *(const float4*)(h12 + (size_t)h2 * 12 + 4);
    const float2 cq2 = *(const float2*)(h12 + (size_t)h2 * 12 + 8);
    const int yh1 = yi[h1], yh2 = yi[h2];
    float loc = 0.0f;

    #pragma unroll 4
    for (int r = 0; r < 128; ++r) {
        const float4 b0  = *(const float4*)(al + r * 12);
        const float4 b1  = *(const float4*)(al + r * 12 + 4);
        const float2 bcq = *(const float2*)(al + r * 12 + 8);
        float acc1 = -cq1.x - bcq.x;
        acc1 = fmaf(p0.x, b0.x, acc1);
        acc1 = fmaf(p0.y, b0.y, acc1);
        acc1 = fmaf(p0.z, b0.z, acc1);
        acc1 = fmaf(p0.w, b0.w, acc1);
        acc1 = fmaf(p1.x, b1.x, acc1);
        acc1 = fmaf(p1.y, b1.y, acc1);
        acc1 = fmaf(p1.z, b1.z, acc1);
        acc1 = fmaf(p1.w, b1.w, acc1);
        float acc2 = -cq2.x - bcq.x;
        acc2 = fmaf(s0.x, b0.x, acc2);
        acc2 = fmaf(s0.y, b0.y, acc2);
        acc2 = fmaf(s0.z, b0.z, acc2);
        acc2 = fmaf(s0.w, b0.w, acc2);
        acc2 = fmaf(s1.x, b1.x, acc2);
        acc2 = fmaf(s1.y, b1.y, acc2);
        acc2 = fmaf(s1.z, b1.z, acc2);
        acc2 = fmaf(s1.w, b1.w, acc2);
        if (acc1 > 0.0f) {          // rare: d2 over first 8 dims < 1
            const int kg = k0 + r;
            if (yh1 != kg) {
                float d2 = 1.0f - 2.0f * acc1;
                const float* hp  = ox + (size_t)h1 * DD;
                const float* apf = xa + (size_t)kg * DD;
                #pragma unroll
                for (int d = 8; d < DD; d += 4) {
                    float4 av = *(const float4*)(hp + d);
                    float4 bv = *(const float4*)(apf + d);
                    float dx = av.x - bv.x; d2 = fmaf(dx, dx, d2);
                    float dy = av.y - bv.y; d2 = fmaf(dy, dy, d2);
                    float dz = av.z - bv.z; d2 = fmaf(dz, dz, d2);
                    float dw = av.w - bv.w; d2 = fmaf(dw, dw, d2);
                }
                float dist = sqrtf(fmaxf(d2, 0.0f) + 1e-12f);
                float hin  = 1.0f - dist;
                if (hin > 0.0f) loc += cq1.y * bcq.y * hin;
            }
        }
        if (acc2 > 0.0f) {
            const int kg = k0 + r;
            if (yh2 != kg) {
                float d2 = 1.0f - 2.0f * acc2;
                const float* hp  = ox + (size_t)h2 * DD;
                const float* apf = xa + (size_t)kg * DD;
                #pragma unroll
                for (int d = 8; d < DD; d += 4) {
                    float4 av = *(const float4*)(hp + d);
                    float4 bv = *(const float4*)(apf + d);
                    float dx = av.x - bv.x; d2 = fmaf(dx, dx, d2);
                    float dy = av.y - bv.y; d2 = fmaf(dy, dy, d2);
                    float dz = av.z - bv.z; d2 = fmaf(dz, dz, d2);
                    float dw = av.w - bv.w; d2 = fmaf(dw, dw, d2);
                }
                float dist = sqrtf(fmaxf(d2, 0.0f) + 1e-12f);
                float hin  = 1.0f - dist;
                if (hin > 0.0f) loc += cq2.y * bcq.y * hin;
            }
        }
    }
    for (int off = 32; off > 0; off >>= 1) loc += __shfl_down(loc, off);
    __shared__ float red[4];
    if ((t & 63) == 0) red[t >> 6] = loc;
    __syncthreads();
    if (t == 0) atomicAdd(part + 0, red[0] + red[1] + red[2] + red[3]);
}

__global__ void k_final(const float* __restrict__ temp, float* __restrict__ ws,
                        float* __restrict__ out) {
    float vrep  = ws[WS_PART + 0];
    float vatt  = ws[WS_PART + 1];
    float nsum  = ws[WS_PART + 2];
    unsigned nn = *(const unsigned int*)(ws + WS_PART + 3);
    float somba = ws[WS_PART + 4];
    float lb = somba * (1.0f / (float)KI) + nsum / (float)(nn < 1u ? 1u : nn);
    float lv = (vatt + vrep) / (float)NH;
    float tv = temp[0];
    out[0] = (lb + lv) * expf(-tv) + tv;
}

extern "C" void kernel_launch(void* const* d_in, const int* in_sizes, int n_in,
                              void* d_out, int out_size, void* d_ws, size_t ws_size,
                              hipStream_t stream) {
    const float* x    = (const float*)d_in[0];
    const float* Wb   = (const float*)d_in[1];
    const float* bb   = (const float*)d_in[2];
    const float* Wc   = (const float*)d_in[3];
    const float* bcrd = (const float*)d_in[4];
    const float* temp = (const float*)d_in[5];
    const int*   yi   = (const int*)d_in[6];
    const int*   ep   = (const int*)d_in[8];
    const int E = in_sizes[8] / 2;
    const int* eh = ep;
    const int* ei = ep + E;
    float* ws  = (float*)d_ws;
    float* out = (float*)d_out;

    k_prep<<<33, 256, 0, stream>>>(Wc, Wb, ws);
    k_gemm<<<NH / 64, 256, 0, stream>>>(x, bb, bcrd, yi, ws);
    const int eb = (E + 255) / 256;
    k_segmax<<<eb, 256, 0, stream>>>(eh, ei, E, ws + WS_H12,
                                     (unsigned long long*)(ws + WS_SEG64));
    k_gather<<<KI / 256, 256, 0, stream>>>(ws);
    k_att<<<eb, 256, 0, stream>>>(eh, ei, E, ws);
    k_rep<<<96 * 8, 256, 0, stream>>>(yi, ws + WS_A12, ws + WS_H12,
                                      ws + WS_OX, ws + WS_XA, ws);
    k_final<<<1, 1, 0, stream>>>(temp, ws, out);
}